// Round 15
// baseline (236.387 us; speedup 1.0000x reference)
//
#include <hip/hip_runtime.h>
#include <hip/hip_bf16.h>
#include <stdint.h>

constexpr int NN = 1024;   // nodes
constexpr int DD = 128;    // NODE_DIM == HID
constexpr int EDIM = 32;   // EDGE_DIM
constexpr int NR = 16;     // NREL

using short4v = __attribute__((ext_vector_type(4))) short;
using short8v = __attribute__((ext_vector_type(8))) short;
using f32x4   = __attribute__((ext_vector_type(4))) float;

__device__ __forceinline__ short f2bf(float x) {
  __hip_bfloat16 h = __float2bfloat16(x);   // RNE
  return __builtin_bit_cast(short, h);
}

__device__ __forceinline__ void nt_store4(float* p, const f32x4& v) {
  __builtin_nontemporal_store(v, (f32x4*)p);
}

// ---------------- K_adjmm (v2: fused f32->bf16 transpose stage + MFMA) ----------
// part[kc][i][h] = sum_{k in kc} adj[i][k] * X[k][h]
// Block b = kc*64 + hc*16 + ic: K-chunk 256, h-chunk 32, i-chunk 64 (wave=16 i).
// Stage X[k0:k0+256][h0:h0+32] -> xt[h][k] bf16 in LDS (pad 264: A-frag reads
// 2-way conflict = free). B-frag = adj rows f32->bf16 in-reg (B[k][col=i]).
__global__ __launch_bounds__(256) void k_adjmm(const float* __restrict__ X,
                                               const float* __restrict__ adj,
                                               float* __restrict__ part) {
  __shared__ short xt[32][264];            // 16.5 KB
  int t = threadIdx.x;
  int w = t >> 6, lane = t & 63;
  int c = lane & 15, g = lane >> 4;
  int b = blockIdx.x;
  int ic = b & 15, hc = (b >> 4) & 3, kc = b >> 6;
  int i0 = ic * 64 + w * 16, h0 = hc * 32;
  int k0 = kc * 256;

  {  // thread t stages row k = k0+t (32 floats from h0) into column t of xt
    const float* xr = X + (size_t)(k0 + t) * DD + h0;
    #pragma unroll
    for (int c8 = 0; c8 < 4; ++c8) {
      float4 v0 = *(const float4*)(xr + c8 * 8);
      float4 v1 = *(const float4*)(xr + c8 * 8 + 4);
      xt[c8 * 8 + 0][t] = f2bf(v0.x);
      xt[c8 * 8 + 1][t] = f2bf(v0.y);
      xt[c8 * 8 + 2][t] = f2bf(v0.z);
      xt[c8 * 8 + 3][t] = f2bf(v0.w);
      xt[c8 * 8 + 4][t] = f2bf(v1.x);
      xt[c8 * 8 + 5][t] = f2bf(v1.y);
      xt[c8 * 8 + 6][t] = f2bf(v1.z);
      xt[c8 * 8 + 7][t] = f2bf(v1.w);
    }
  }
  __syncthreads();

  f32x4 acc0 = {0, 0, 0, 0}, acc1 = {0, 0, 0, 0};
  const short* xa0 = &xt[c][8 * g];
  const short* xa1 = &xt[16 + c][8 * g];
  const float* ba  = adj + (size_t)(i0 + c) * NN + k0 + 8 * g;
  #pragma unroll
  for (int ks = 0; ks < 8; ++ks) {
    short8v a0 = *(const short8v*)(xa0 + ks * 32);
    short8v a1 = *(const short8v*)(xa1 + ks * 32);
    float4 b0 = *(const float4*)(ba + ks * 32);
    float4 b1 = *(const float4*)(ba + ks * 32 + 4);
    short8v bb;
    bb[0] = f2bf(b0.x); bb[1] = f2bf(b0.y); bb[2] = f2bf(b0.z); bb[3] = f2bf(b0.w);
    bb[4] = f2bf(b1.x); bb[5] = f2bf(b1.y); bb[6] = f2bf(b1.z); bb[7] = f2bf(b1.w);
    acc0 = __builtin_amdgcn_mfma_f32_16x16x32_bf16(a0, bb, acc0, 0, 0, 0);
    acc1 = __builtin_amdgcn_mfma_f32_16x16x32_bf16(a1, bb, acc1, 0, 0, 0);
  }
  float* p0 = part + ((size_t)kc * NN + (i0 + c)) * DD + h0 + 4 * g;
  float4 o0 = {acc0[0], acc0[1], acc0[2], acc0[3]};
  float4 o1 = {acc1[0], acc1[1], acc1[2], acc1[3]};
  *(float4*)(p0)      = o0;
  *(float4*)(p0 + 16) = o1;
}

// ---------------- K_dense1: rowsum + aggfin + dense layer1 ----------------
__global__ __launch_bounds__(256) void k_dense1(const float* __restrict__ X,
                                                const float* __restrict__ part,
                                                const float* __restrict__ adj,
                                                const float* __restrict__ W,
                                                const float* __restrict__ b,
                                                float* __restrict__ out,
                                                float* __restrict__ rsinv) {
  __shared__ float sagg[2][128];
  __shared__ float red[4];
  int t = threadIdx.x;
  int ig = t >> 7, h = t & 127;
  int i = blockIdx.x * 2 + ig;
  {
    const float4* ar = (const float4*)(adj + (size_t)i * NN);
    float4 v0 = ar[h * 2], v1 = ar[h * 2 + 1];
    float s = v0.x + v0.y + v0.z + v0.w + v1.x + v1.y + v1.z + v1.w;
    #pragma unroll
    for (int off = 32; off > 0; off >>= 1) s += __shfl_down(s, off, 64);
    if ((t & 63) == 0) red[t >> 6] = s;
  }
  __syncthreads();
  float rs = 1.0f / (red[ig * 2] + red[ig * 2 + 1] + 1e-6f);
  if (h == 0) rsinv[i] = rs;
  {
    float ss = 0.f;
    #pragma unroll
    for (int kc = 0; kc < 4; ++kc) ss += part[(size_t)kc * NN * DD + (size_t)i * DD + h];
    sagg[ig][h] = ss * rs;
  }
  __syncthreads();
  const float4* xr = (const float4*)(X + (size_t)i * DD);
  const float4* ar = (const float4*)(&sagg[ig][0]);
  const float4* w1 = (const float4*)(W + (size_t)h * 256);
  const float4* w2 = (const float4*)(W + (size_t)h * 256 + DD);
  float acc = b[h];
  #pragma unroll 8
  for (int k = 0; k < 32; ++k) {
    float4 x = xr[k], w = w1[k];
    acc += x.x * w.x + x.y * w.y + x.z * w.z + x.w * w.w;
  }
  #pragma unroll 8
  for (int k = 0; k < 32; ++k) {
    float4 y = ar[k], w = w2[k];
    acc += y.x * w.x + y.y * w.y + y.z * w.z + y.w * w.w;
  }
  out[(size_t)i * DD + h] = fmaxf(acc, 0.f);
}

// ---------------- K_dense2ab: aggfin + dense layer2 + Aib/Bmat, fused ------------
__global__ __launch_bounds__(256) void k_dense2ab(const float* __restrict__ X,
                                                  const float* __restrict__ part,
                                                  const float* __restrict__ rsinv,
                                                  const float* __restrict__ W,
                                                  const float* __restrict__ b,
                                                  const float* __restrict__ Wc1,
                                                  const float* __restrict__ bc1,
                                                  float* __restrict__ Aib,
                                                  float* __restrict__ Bmat) {
  __shared__ float sagg[2][128];
  __shared__ float sh2[2][128];
  int t = threadIdx.x;
  int ig = t >> 7, h = t & 127;
  int i = blockIdx.x * 2 + ig;
  {
    float ss = 0.f;
    #pragma unroll
    for (int kc = 0; kc < 4; ++kc) ss += part[(size_t)kc * NN * DD + (size_t)i * DD + h];
    sagg[ig][h] = ss * rsinv[i];
  }
  __syncthreads();
  {
    const float4* xr = (const float4*)(X + (size_t)i * DD);
    const float4* ar = (const float4*)(&sagg[ig][0]);
    const float4* w1 = (const float4*)(W + (size_t)h * 256);
    const float4* w2 = (const float4*)(W + (size_t)h * 256 + DD);
    float acc = b[h];
    #pragma unroll 8
    for (int k = 0; k < 32; ++k) {
      float4 x = xr[k], w = w1[k];
      acc += x.x * w.x + x.y * w.y + x.z * w.z + x.w * w.w;
    }
    #pragma unroll 8
    for (int k = 0; k < 32; ++k) {
      float4 y = ar[k], w = w2[k];
      acc += y.x * w.x + y.y * w.y + y.z * w.z + y.w * w.w;
    }
    sh2[ig][h] = fmaxf(acc, 0.f);
  }
  __syncthreads();
  const float4* xr = (const float4*)(&sh2[ig][0]);
  const float4* wa = (const float4*)(Wc1 + (size_t)h * 288);
  const float4* wb = (const float4*)(Wc1 + (size_t)h * 288 + 128);
  float aa = bc1[h], bb = 0.f;
  #pragma unroll 8
  for (int k = 0; k < 32; ++k) {
    float4 x = xr[k];
    float4 a = wa[k], b2 = wb[k];
    aa += x.x * a.x + x.y * a.y + x.z * a.z + x.w * a.w;
    bb += x.x * b2.x + x.y * b2.y + x.z * b2.z + x.w * b2.w;
  }
  Aib[(size_t)i * DD + h] = aa;
  Bmat[(size_t)i * DD + h] = bb;
}

// ---------------- K7: fused edge stage (v13: reg-diet for 3 waves/SIMD) ----------
// State cuts vs v12: bjv -> per-body L2 re-read of Bmat (-32 regs), edge
// rotation 6->4 (-16), per-body store (-12). Working set ~140-160 regs, so
// __launch_bounds__(256,3)'s 170-reg budget fits WITHOUT spill -> 12 waves/CU.

#define EDGE_BODY(T, S, PF) do {                                              \
    float4 a_ = eA##S, b_ = eB##S;                                            \
    if (PF) {                                                                 \
      const float* p_ = ebl + (size_t)((T) + 4) * ((size_t)NN * EDIM);        \
      eA##S = *(const float4*)p_;                                             \
      eB##S = *(const float4*)(p_ + 4);                                       \
    }                                                                         \
    short8v ef_;                                                              \
    ef_[0]=f2bf(a_.x); ef_[1]=f2bf(a_.y); ef_[2]=f2bf(a_.z); ef_[3]=f2bf(a_.w); \
    ef_[4]=f2bf(b_.x); ef_[5]=f2bf(b_.y); ef_[6]=f2bf(b_.z); ef_[7]=f2bf(b_.w); \
    char* pw_ = psm + (((T) & 1) << 12);                                      \
    const float* ap_ = aibs + (T) * 128 + 4 * g;                              \
    _Pragma("unroll")                                                         \
    for (int n = 0; n < 8; ++n) {                                             \
      float4 av_ = *(const float4*)(ap_ + 16 * n);                            \
      float4 bv_ = *(const float4*)(bp + 16 * n);   /* Bmat, L2-hot */        \
      f32x4 ci_;                                                              \
      ci_[0] = av_.x + bv_.x; ci_[1] = av_.y + bv_.y;                         \
      ci_[2] = av_.z + bv_.z; ci_[3] = av_.w + bv_.w;                         \
      f32x4 acc_ = __builtin_amdgcn_mfma_f32_16x16x32_bf16(weF[n], ef_, ci_, 0, 0, 0); \
      short4v pk_;                                                            \
      pk_[0] = f2bf(fmaxf(acc_[0], 0.f)); pk_[1] = f2bf(fmaxf(acc_[1], 0.f)); \
      pk_[2] = f2bf(fmaxf(acc_[2], 0.f)); pk_[3] = f2bf(fmaxf(acc_[3], 0.f)); \
      *(short4v*)(pw_ + (((n >> 1) << 10) + ((n & 1) << 9) + wroff)) = pk_;   \
    }                                                                         \
  } while (0)

// GEMM2 for body G2T (P in psm[(G2T)&1]) + immediate nontemporal store
#define G2_ST(G2T) do {                                                       \
    f32x4 a2_;                                                                \
    a2_[0] = bc2v.x; a2_[1] = bc2v.y; a2_[2] = bc2v.z; a2_[3] = bc2v.w;       \
    const char* pp_ = psm + (((G2T) & 1) << 12);                              \
    _Pragma("unroll")                                                         \
    for (int kk = 0; kk < 4; ++kk) {                                          \
      short8v pb_ = *(const short8v*)(pp_ + ((kk << 10) + rdP));              \
      a2_ = __builtin_amdgcn_mfma_f32_16x16x32_bf16(wcF[kk], pb_, a2_, 0, 0, 0); \
    }                                                                         \
    bool dg_ = (j == i0 + (G2T));                                             \
    f32x4 o_;                                                                 \
    o_[0] = dg_ ? 0.f : a2_[0];                                               \
    o_[1] = dg_ ? 0.f : a2_[1];                                               \
    o_[2] = dg_ ? 0.f : a2_[2];                                               \
    o_[3] = dg_ ? 0.f : a2_[3];                                               \
    nt_store4(out + ((size_t)(i0 + (G2T)) * NN + j) * NR + 4 * g, o_);        \
  } while (0)

__global__ __launch_bounds__(256, 3) void k_edge(const float* __restrict__ edge,
                                                 const float* __restrict__ Wc1,
                                                 const float* __restrict__ Wc2,
                                                 const float* __restrict__ bc2,
                                                 const float* __restrict__ Aib,
                                                 const float* __restrict__ Bmat,
                                                 float* __restrict__ out) {
  __shared__ __align__(16) char psm_all[4][2][4096]; // 32 KB P tiles (dbuf per wave)
  __shared__ __align__(16) float aibs[16 * 128];     // 8 KB Aib panel -> 40 KB total
  int tid = threadIdx.x;
  int w = tid >> 6, lane = tid & 63;
  int c = lane & 15, g = lane >> 4;
  int ig = blockIdx.x >> 4, jg = blockIdx.x & 15;
  int i0 = ig * 16;
  int j0w = jg * 64 + w * 16;
  int j = j0w + c;

  {
    int ii = tid >> 4, h8 = (tid & 15) * 8;
    const float4* s = (const float4*)(Aib + (size_t)(i0 + ii) * DD + h8);
    *(float4*)(aibs + ii * 128 + h8)     = s[0];
    *(float4*)(aibs + ii * 128 + h8 + 4) = s[1];
  }

  short8v weF[8];
  #pragma unroll
  for (int n = 0; n < 8; ++n) {
    const float* p = Wc1 + (size_t)(16 * n + c) * 288 + 256 + 8 * g;
    float4 f0 = *(const float4*)p;
    float4 f1 = *(const float4*)(p + 4);
    short8v s;
    s[0]=f2bf(f0.x); s[1]=f2bf(f0.y); s[2]=f2bf(f0.z); s[3]=f2bf(f0.w);
    s[4]=f2bf(f1.x); s[5]=f2bf(f1.y); s[6]=f2bf(f1.z); s[7]=f2bf(f1.w);
    weF[n] = s;
  }
  short8v wcF[4];
  #pragma unroll
  for (int kk = 0; kk < 4; ++kk) {
    const float* p = Wc2 + (size_t)c * DD + 32 * kk + 8 * g;
    float4 f0 = *(const float4*)p;
    float4 f1 = *(const float4*)(p + 4);
    short8v s;
    s[0]=f2bf(f0.x); s[1]=f2bf(f0.y); s[2]=f2bf(f0.z); s[3]=f2bf(f0.w);
    s[4]=f2bf(f1.x); s[5]=f2bf(f1.y); s[6]=f2bf(f1.z); s[7]=f2bf(f1.w);
    wcF[kk] = s;
  }
  float4 bc2v = *(const float4*)(bc2 + 4 * g);
  const float* bp = Bmat + (size_t)j * DD + 4 * g;   // per-body Bmat reads (L2)

  __syncthreads();   // aibs ready

  char* psm = &psm_all[w][0][0];
  const float* ebl = edge + ((size_t)i0 * NN + j) * EDIM + 8 * g;
  int wroff = (c << 4) + ((g & 1) << 3) + ((g >> 1) << 8);
  int rdP   = (g << 8) + (c << 4);

  // prologue: fill rotation slots 0..3 with bodies 0..3 (8 loads in flight)
  float4 eA0, eB0, eA1, eB1, eA2, eB2, eA3, eB3;
  {
    const size_t STP = (size_t)NN * EDIM;
    eA0 = *(const float4*)(ebl);            eB0 = *(const float4*)(ebl + 4);
    eA1 = *(const float4*)(ebl + STP);      eB1 = *(const float4*)(ebl + STP + 4);
    eA2 = *(const float4*)(ebl + 2 * STP);  eB2 = *(const float4*)(ebl + 2 * STP + 4);
    eA3 = *(const float4*)(ebl + 3 * STP);  eB3 = *(const float4*)(ebl + 3 * STP + 4);
  }

  EDGE_BODY(0,  0, 1);
  EDGE_BODY(1,  1, 1);  G2_ST(0);
  EDGE_BODY(2,  2, 1);  G2_ST(1);
  EDGE_BODY(3,  3, 1);  G2_ST(2);
  EDGE_BODY(4,  0, 1);  G2_ST(3);
  EDGE_BODY(5,  1, 1);  G2_ST(4);
  EDGE_BODY(6,  2, 1);  G2_ST(5);
  EDGE_BODY(7,  3, 1);  G2_ST(6);
  EDGE_BODY(8,  0, 1);  G2_ST(7);
  EDGE_BODY(9,  1, 1);  G2_ST(8);
  EDGE_BODY(10, 2, 1);  G2_ST(9);
  EDGE_BODY(11, 3, 1);  G2_ST(10);
  EDGE_BODY(12, 0, 0);  G2_ST(11);
  EDGE_BODY(13, 1, 0);  G2_ST(12);
  EDGE_BODY(14, 2, 0);  G2_ST(13);
  EDGE_BODY(15, 3, 0);  G2_ST(14);
  G2_ST(15);
}

extern "C" void kernel_launch(void* const* d_in, const int* in_sizes, int n_in,
                              void* d_out, int out_size, void* d_ws, size_t ws_size,
                              hipStream_t stream) {
  const float* node_feat = (const float*)d_in[0];
  const float* edge_feat = (const float*)d_in[1];
  const float* adj  = (const float*)d_in[2];
  const float* W_g1 = (const float*)d_in[3];
  const float* b_g1 = (const float*)d_in[4];
  const float* W_g2 = (const float*)d_in[5];
  const float* b_g2 = (const float*)d_in[6];
  const float* W_c1 = (const float*)d_in[7];
  const float* b_c1 = (const float*)d_in[8];
  const float* W_c2 = (const float*)d_in[9];
  const float* b_c2 = (const float*)d_in[10];
  float* out = (float*)d_out;

  float* ws    = (float*)d_ws;
  float* rsinv = ws;                        // 1024
  float* part  = ws + 1024;                 // 4*1024*128 = 524288
  float* h1    = part + 4 * NN * DD;        // 131072
  float* Aib   = h1 + NN * DD;              // 131072
  float* Bmat  = Aib + NN * DD;             // 131072

  // layer 1: fused-transpose MFMA adj@X -> dense (rowsum fused)
  k_adjmm<<<256, 256, 0, stream>>>(node_feat, adj, part);
  k_dense1<<<512, 256, 0, stream>>>(node_feat, part, adj, W_g1, b_g1, h1, rsinv);
  // layer 2
  k_adjmm<<<256, 256, 0, stream>>>(h1, adj, part);
  k_dense2ab<<<512, 256, 0, stream>>>(h1, part, rsinv, W_g2, b_g2, W_c1, b_c1, Aib, Bmat);
  // fused edge stage
  k_edge<<<1024, 256, 0, stream>>>(edge_feat, W_c1, W_c2, b_c2, Aib, Bmat, out);
}

// Round 16
// 115.428 us; speedup vs baseline: 2.0479x; 2.0479x over previous
//
#include <hip/hip_runtime.h>
#include <hip/hip_bf16.h>
#include <stdint.h>

constexpr int NN = 1024;   // nodes
constexpr int DD = 128;    // NODE_DIM == HID
constexpr int EDIM = 32;   // EDGE_DIM
constexpr int NR = 16;     // NREL

using short4v = __attribute__((ext_vector_type(4))) short;
using short8v = __attribute__((ext_vector_type(8))) short;
using f32x4   = __attribute__((ext_vector_type(4))) float;

__device__ __forceinline__ short f2bf(float x) {
  __hip_bfloat16 h = __float2bfloat16(x);   // RNE
  return __builtin_bit_cast(short, h);
}

__device__ __forceinline__ void nt_store4(float* p, const float4& v) {
  f32x4 t;
  t[0] = v.x; t[1] = v.y; t[2] = v.z; t[3] = v.w;
  __builtin_nontemporal_store(t, (f32x4*)p);
}

// ---------------- K_adjmm (fused f32->bf16 transpose stage + MFMA) ----------
// part[kc][i][h] = sum_{k in kc} adj[i][k] * X[k][h]
// Block b = kc*64 + hc*16 + ic: K-chunk 256, h-chunk 32, i-chunk 64 (wave=16 i).
__global__ __launch_bounds__(256) void k_adjmm(const float* __restrict__ X,
                                               const float* __restrict__ adj,
                                               float* __restrict__ part) {
  __shared__ short xt[32][264];            // 16.5 KB
  int t = threadIdx.x;
  int w = t >> 6, lane = t & 63;
  int c = lane & 15, g = lane >> 4;
  int b = blockIdx.x;
  int ic = b & 15, hc = (b >> 4) & 3, kc = b >> 6;
  int i0 = ic * 64 + w * 16, h0 = hc * 32;
  int k0 = kc * 256;

  {  // thread t stages row k = k0+t (32 floats from h0) into column t of xt
    const float* xr = X + (size_t)(k0 + t) * DD + h0;
    #pragma unroll
    for (int c8 = 0; c8 < 4; ++c8) {
      float4 v0 = *(const float4*)(xr + c8 * 8);
      float4 v1 = *(const float4*)(xr + c8 * 8 + 4);
      xt[c8 * 8 + 0][t] = f2bf(v0.x);
      xt[c8 * 8 + 1][t] = f2bf(v0.y);
      xt[c8 * 8 + 2][t] = f2bf(v0.z);
      xt[c8 * 8 + 3][t] = f2bf(v0.w);
      xt[c8 * 8 + 4][t] = f2bf(v1.x);
      xt[c8 * 8 + 5][t] = f2bf(v1.y);
      xt[c8 * 8 + 6][t] = f2bf(v1.z);
      xt[c8 * 8 + 7][t] = f2bf(v1.w);
    }
  }
  __syncthreads();

  f32x4 acc0 = {0, 0, 0, 0}, acc1 = {0, 0, 0, 0};
  const short* xa0 = &xt[c][8 * g];
  const short* xa1 = &xt[16 + c][8 * g];
  const float* ba  = adj + (size_t)(i0 + c) * NN + k0 + 8 * g;
  #pragma unroll
  for (int ks = 0; ks < 8; ++ks) {
    short8v a0 = *(const short8v*)(xa0 + ks * 32);
    short8v a1 = *(const short8v*)(xa1 + ks * 32);
    float4 b0 = *(const float4*)(ba + ks * 32);
    float4 b1 = *(const float4*)(ba + ks * 32 + 4);
    short8v bb;
    bb[0] = f2bf(b0.x); bb[1] = f2bf(b0.y); bb[2] = f2bf(b0.z); bb[3] = f2bf(b0.w);
    bb[4] = f2bf(b1.x); bb[5] = f2bf(b1.y); bb[6] = f2bf(b1.z); bb[7] = f2bf(b1.w);
    acc0 = __builtin_amdgcn_mfma_f32_16x16x32_bf16(a0, bb, acc0, 0, 0, 0);
    acc1 = __builtin_amdgcn_mfma_f32_16x16x32_bf16(a1, bb, acc1, 0, 0, 0);
  }
  float* p0 = part + ((size_t)kc * NN + (i0 + c)) * DD + h0 + 4 * g;
  float4 o0 = {acc0[0], acc0[1], acc0[2], acc0[3]};
  float4 o1 = {acc1[0], acc1[1], acc1[2], acc1[3]};
  *(float4*)(p0)      = o0;
  *(float4*)(p0 + 16) = o1;
}

// ---------------- K_dense1: rowsum + aggfin + dense layer1 ----------------
__global__ __launch_bounds__(256) void k_dense1(const float* __restrict__ X,
                                                const float* __restrict__ part,
                                                const float* __restrict__ adj,
                                                const float* __restrict__ W,
                                                const float* __restrict__ b,
                                                float* __restrict__ out,
                                                float* __restrict__ rsinv) {
  __shared__ float sagg[2][128];
  __shared__ float red[4];
  int t = threadIdx.x;
  int ig = t >> 7, h = t & 127;
  int i = blockIdx.x * 2 + ig;
  {
    const float4* ar = (const float4*)(adj + (size_t)i * NN);
    float4 v0 = ar[h * 2], v1 = ar[h * 2 + 1];
    float s = v0.x + v0.y + v0.z + v0.w + v1.x + v1.y + v1.z + v1.w;
    #pragma unroll
    for (int off = 32; off > 0; off >>= 1) s += __shfl_down(s, off, 64);
    if ((t & 63) == 0) red[t >> 6] = s;
  }
  __syncthreads();
  float rs = 1.0f / (red[ig * 2] + red[ig * 2 + 1] + 1e-6f);
  if (h == 0) rsinv[i] = rs;
  {
    float ss = 0.f;
    #pragma unroll
    for (int kc = 0; kc < 4; ++kc) ss += part[(size_t)kc * NN * DD + (size_t)i * DD + h];
    sagg[ig][h] = ss * rs;
  }
  __syncthreads();
  const float4* xr = (const float4*)(X + (size_t)i * DD);
  const float4* ar = (const float4*)(&sagg[ig][0]);
  const float4* w1 = (const float4*)(W + (size_t)h * 256);
  const float4* w2 = (const float4*)(W + (size_t)h * 256 + DD);
  float acc = b[h];
  #pragma unroll 8
  for (int k = 0; k < 32; ++k) {
    float4 x = xr[k], w = w1[k];
    acc += x.x * w.x + x.y * w.y + x.z * w.z + x.w * w.w;
  }
  #pragma unroll 8
  for (int k = 0; k < 32; ++k) {
    float4 y = ar[k], w = w2[k];
    acc += y.x * w.x + y.y * w.y + y.z * w.z + y.w * w.w;
  }
  out[(size_t)i * DD + h] = fmaxf(acc, 0.f);
}

// ---------------- K_dense2ab: aggfin + dense layer2 + Aib/Bmat, fused ------------
__global__ __launch_bounds__(256) void k_dense2ab(const float* __restrict__ X,
                                                  const float* __restrict__ part,
                                                  const float* __restrict__ rsinv,
                                                  const float* __restrict__ W,
                                                  const float* __restrict__ b,
                                                  const float* __restrict__ Wc1,
                                                  const float* __restrict__ bc1,
                                                  float* __restrict__ Aib,
                                                  float* __restrict__ Bmat) {
  __shared__ float sagg[2][128];
  __shared__ float sh2[2][128];
  int t = threadIdx.x;
  int ig = t >> 7, h = t & 127;
  int i = blockIdx.x * 2 + ig;
  {
    float ss = 0.f;
    #pragma unroll
    for (int kc = 0; kc < 4; ++kc) ss += part[(size_t)kc * NN * DD + (size_t)i * DD + h];
    sagg[ig][h] = ss * rsinv[i];
  }
  __syncthreads();
  {
    const float4* xr = (const float4*)(X + (size_t)i * DD);
    const float4* ar = (const float4*)(&sagg[ig][0]);
    const float4* w1 = (const float4*)(W + (size_t)h * 256);
    const float4* w2 = (const float4*)(W + (size_t)h * 256 + DD);
    float acc = b[h];
    #pragma unroll 8
    for (int k = 0; k < 32; ++k) {
      float4 x = xr[k], w = w1[k];
      acc += x.x * w.x + x.y * w.y + x.z * w.z + x.w * w.w;
    }
    #pragma unroll 8
    for (int k = 0; k < 32; ++k) {
      float4 y = ar[k], w = w2[k];
      acc += y.x * w.x + y.y * w.y + y.z * w.z + y.w * w.w;
    }
    sh2[ig][h] = fmaxf(acc, 0.f);
  }
  __syncthreads();
  const float4* xr = (const float4*)(&sh2[ig][0]);
  const float4* wa = (const float4*)(Wc1 + (size_t)h * 288);
  const float4* wb = (const float4*)(Wc1 + (size_t)h * 288 + 128);
  float aa = bc1[h], bb = 0.f;
  #pragma unroll 8
  for (int k = 0; k < 32; ++k) {
    float4 x = xr[k];
    float4 a = wa[k], b2 = wb[k];
    aa += x.x * a.x + x.y * a.y + x.z * a.z + x.w * a.w;
    bb += x.x * b2.x + x.y * b2.y + x.z * b2.z + x.w * b2.w;
  }
  Aib[(size_t)i * DD + h] = aa;
  Bmat[(size_t)i * DD + h] = bb;
}

// ---------------- K7: fused edge stage (v12, reverted from R14 — measured 77 µs) --
#define EDGE_BODY(T, S, PF) do {                                              \
    float4 a_ = eA##S, b_ = eB##S;                                            \
    if (PF) {                                                                 \
      const float* p_ = ebl + (size_t)((T) + 6) * ((size_t)NN * EDIM);        \
      eA##S = *(const float4*)p_;                                             \
      eB##S = *(const float4*)(p_ + 4);                                       \
    }                                                                         \
    short8v ef_;                                                              \
    ef_[0]=f2bf(a_.x); ef_[1]=f2bf(a_.y); ef_[2]=f2bf(a_.z); ef_[3]=f2bf(a_.w); \
    ef_[4]=f2bf(b_.x); ef_[5]=f2bf(b_.y); ef_[6]=f2bf(b_.z); ef_[7]=f2bf(b_.w); \
    char* pw_ = psm + (((T) & 1) << 12);                                      \
    const float* ap_ = aibs + (T) * 128 + 4 * g;                              \
    _Pragma("unroll")                                                         \
    for (int n = 0; n < 8; ++n) {                                             \
      float4 av_ = *(const float4*)(ap_ + 16 * n);                            \
      f32x4 ci_;                                                              \
      ci_[0] = av_.x + bjv[n].x; ci_[1] = av_.y + bjv[n].y;                   \
      ci_[2] = av_.z + bjv[n].z; ci_[3] = av_.w + bjv[n].w;                   \
      f32x4 acc_ = __builtin_amdgcn_mfma_f32_16x16x32_bf16(weF[n], ef_, ci_, 0, 0, 0); \
      short4v pk_;                                                            \
      pk_[0] = f2bf(fmaxf(acc_[0], 0.f)); pk_[1] = f2bf(fmaxf(acc_[1], 0.f)); \
      pk_[2] = f2bf(fmaxf(acc_[2], 0.f)); pk_[3] = f2bf(fmaxf(acc_[3], 0.f)); \
      *(short4v*)(pw_ + (((n >> 1) << 10) + ((n & 1) << 9) + wroff)) = pk_;   \
    }                                                                         \
  } while (0)

#define G2(G2T, OREG) do {                                                    \
    f32x4 a2_;                                                                \
    a2_[0] = bc2v.x; a2_[1] = bc2v.y; a2_[2] = bc2v.z; a2_[3] = bc2v.w;       \
    const char* pp_ = psm + (((G2T) & 1) << 12);                              \
    _Pragma("unroll")                                                         \
    for (int kk = 0; kk < 4; ++kk) {                                          \
      short8v pb_ = *(const short8v*)(pp_ + ((kk << 10) + rdP));              \
      a2_ = __builtin_amdgcn_mfma_f32_16x16x32_bf16(wcF[kk], pb_, a2_, 0, 0, 0); \
    }                                                                         \
    bool dg_ = (j == i0 + (G2T));                                             \
    OREG.x = dg_ ? 0.f : a2_[0];                                              \
    OREG.y = dg_ ? 0.f : a2_[1];                                              \
    OREG.z = dg_ ? 0.f : a2_[2];                                              \
    OREG.w = dg_ ? 0.f : a2_[3];                                              \
  } while (0)

#define FLUSH(BASE) do {                                                      \
    nt_store4(out + ((size_t)(i0 + (BASE) + 0) * NN + j) * NR + 4 * g, o0);   \
    nt_store4(out + ((size_t)(i0 + (BASE) + 1) * NN + j) * NR + 4 * g, o1);   \
    nt_store4(out + ((size_t)(i0 + (BASE) + 2) * NN + j) * NR + 4 * g, o2);   \
    nt_store4(out + ((size_t)(i0 + (BASE) + 3) * NN + j) * NR + 4 * g, o3);   \
  } while (0)

__global__ __launch_bounds__(256, 1) void k_edge(const float* __restrict__ edge,
                                                 const float* __restrict__ Wc1,
                                                 const float* __restrict__ Wc2,
                                                 const float* __restrict__ bc2,
                                                 const float* __restrict__ Aib,
                                                 const float* __restrict__ Bmat,
                                                 float* __restrict__ out) {
  __shared__ __align__(16) char psm_all[4][2][4096]; // 32 KB P tiles (dbuf per wave)
  __shared__ __align__(16) float aibs[16 * 128];     // 8 KB Aib panel -> 40 KB total
  int tid = threadIdx.x;
  int w = tid >> 6, lane = tid & 63;
  int c = lane & 15, g = lane >> 4;
  int ig = blockIdx.x >> 4, jg = blockIdx.x & 15;
  int i0 = ig * 16;
  int j0w = jg * 64 + w * 16;
  int j = j0w + c;

  {
    int ii = tid >> 4, h8 = (tid & 15) * 8;
    const float4* s = (const float4*)(Aib + (size_t)(i0 + ii) * DD + h8);
    *(float4*)(aibs + ii * 128 + h8)     = s[0];
    *(float4*)(aibs + ii * 128 + h8 + 4) = s[1];
  }

  short8v weF[8];
  #pragma unroll
  for (int n = 0; n < 8; ++n) {
    const float* p = Wc1 + (size_t)(16 * n + c) * 288 + 256 + 8 * g;
    float4 f0 = *(const float4*)p;
    float4 f1 = *(const float4*)(p + 4);
    short8v s;
    s[0]=f2bf(f0.x); s[1]=f2bf(f0.y); s[2]=f2bf(f0.z); s[3]=f2bf(f0.w);
    s[4]=f2bf(f1.x); s[5]=f2bf(f1.y); s[6]=f2bf(f1.z); s[7]=f2bf(f1.w);
    weF[n] = s;
  }
  short8v wcF[4];
  #pragma unroll
  for (int kk = 0; kk < 4; ++kk) {
    const float* p = Wc2 + (size_t)c * DD + 32 * kk + 8 * g;
    float4 f0 = *(const float4*)p;
    float4 f1 = *(const float4*)(p + 4);
    short8v s;
    s[0]=f2bf(f0.x); s[1]=f2bf(f0.y); s[2]=f2bf(f0.z); s[3]=f2bf(f0.w);
    s[4]=f2bf(f1.x); s[5]=f2bf(f1.y); s[6]=f2bf(f1.z); s[7]=f2bf(f1.w);
    wcF[kk] = s;
  }
  float4 bc2v = *(const float4*)(bc2 + 4 * g);
  float4 bjv[8];
  #pragma unroll
  for (int n = 0; n < 8; ++n)
    bjv[n] = *(const float4*)(Bmat + (size_t)j * DD + 16 * n + 4 * g);

  __syncthreads();   // aibs ready

  char* psm = &psm_all[w][0][0];
  const float* ebl = edge + ((size_t)i0 * NN + j) * EDIM + 8 * g;
  int wroff = (c << 4) + ((g & 1) << 3) + ((g >> 1) << 8);
  int rdP   = (g << 8) + (c << 4);

  float4 o0, o1, o2, o3;

  float4 eA0, eB0, eA1, eB1, eA2, eB2, eA3, eB3, eA4, eB4, eA5, eB5;
  {
    const size_t STP = (size_t)NN * EDIM;
    eA0 = *(const float4*)(ebl);            eB0 = *(const float4*)(ebl + 4);
    eA1 = *(const float4*)(ebl + STP);      eB1 = *(const float4*)(ebl + STP + 4);
    eA2 = *(const float4*)(ebl + 2 * STP);  eB2 = *(const float4*)(ebl + 2 * STP + 4);
    eA3 = *(const float4*)(ebl + 3 * STP);  eB3 = *(const float4*)(ebl + 3 * STP + 4);
    eA4 = *(const float4*)(ebl + 4 * STP);  eB4 = *(const float4*)(ebl + 4 * STP + 4);
    eA5 = *(const float4*)(ebl + 5 * STP);  eB5 = *(const float4*)(ebl + 5 * STP + 4);
  }

  EDGE_BODY(0, 0, 1);
  EDGE_BODY(1, 1, 1);  G2(0, o0);
  EDGE_BODY(2, 2, 1);  G2(1, o1);
  EDGE_BODY(3, 3, 1);  G2(2, o2);
  EDGE_BODY(4, 4, 1);  G2(3, o3);  FLUSH(0);
  EDGE_BODY(5, 5, 1);  G2(4, o0);
  EDGE_BODY(6, 0, 1);  G2(5, o1);
  EDGE_BODY(7, 1, 1);  G2(6, o2);
  EDGE_BODY(8, 2, 1);  G2(7, o3);  FLUSH(4);
  EDGE_BODY(9, 3, 1);  G2(8, o0);
  EDGE_BODY(10, 4, 0); G2(9, o1);
  EDGE_BODY(11, 5, 0); G2(10, o2);
  EDGE_BODY(12, 0, 0); G2(11, o3); FLUSH(8);
  EDGE_BODY(13, 1, 0); G2(12, o0);
  EDGE_BODY(14, 2, 0); G2(13, o1);
  EDGE_BODY(15, 3, 0); G2(14, o2);
  G2(15, o3); FLUSH(12);
}

extern "C" void kernel_launch(void* const* d_in, const int* in_sizes, int n_in,
                              void* d_out, int out_size, void* d_ws, size_t ws_size,
                              hipStream_t stream) {
  const float* node_feat = (const float*)d_in[0];
  const float* edge_feat = (const float*)d_in[1];
  const float* adj  = (const float*)d_in[2];
  const float* W_g1 = (const float*)d_in[3];
  const float* b_g1 = (const float*)d_in[4];
  const float* W_g2 = (const float*)d_in[5];
  const float* b_g2 = (const float*)d_in[6];
  const float* W_c1 = (const float*)d_in[7];
  const float* b_c1 = (const float*)d_in[8];
  const float* W_c2 = (const float*)d_in[9];
  const float* b_c2 = (const float*)d_in[10];
  float* out = (float*)d_out;

  float* ws    = (float*)d_ws;
  float* rsinv = ws;                        // 1024
  float* part  = ws + 1024;                 // 4*1024*128 = 524288
  float* h1    = part + 4 * NN * DD;        // 131072
  float* Aib   = h1 + NN * DD;              // 131072
  float* Bmat  = Aib + NN * DD;             // 131072

  // layer 1: fused-transpose MFMA adj@X -> dense (rowsum fused)
  k_adjmm<<<256, 256, 0, stream>>>(node_feat, adj, part);
  k_dense1<<<512, 256, 0, stream>>>(node_feat, part, adj, W_g1, b_g1, h1, rsinv);
  // layer 2
  k_adjmm<<<256, 256, 0, stream>>>(h1, adj, part);
  k_dense2ab<<<512, 256, 0, stream>>>(h1, part, rsinv, W_g2, b_g2, W_c1, b_c1, Aib, Bmat);
  // fused edge stage (R14 v12 revert)
  k_edge<<<1024, 256, 0, stream>>>(edge_feat, W_c1, W_c2, b_c2, Aib, Bmat, out);
}

// Round 17
// 115.358 us; speedup vs baseline: 2.0492x; 1.0006x over previous
//
#include <hip/hip_runtime.h>
#include <hip/hip_bf16.h>
#include <stdint.h>

constexpr int NN = 1024;   // nodes
constexpr int DD = 128;    // NODE_DIM == HID
constexpr int EDIM = 32;   // EDGE_DIM
constexpr int NR = 16;     // NREL

using short4v = __attribute__((ext_vector_type(4))) short;
using short8v = __attribute__((ext_vector_type(8))) short;
using f32x4   = __attribute__((ext_vector_type(4))) float;

__device__ __forceinline__ short f2bf(float x) {
  __hip_bfloat16 h = __float2bfloat16(x);   // RNE
  return __builtin_bit_cast(short, h);
}

__device__ __forceinline__ void nt_store4(float* p, const float4& v) {
  f32x4 t;
  t[0] = v.x; t[1] = v.y; t[2] = v.z; t[3] = v.w;
  __builtin_nontemporal_store(t, (f32x4*)p);
}

// ---------------- K_adjmm (fused f32->bf16 transpose stage + MFMA) ----------
// part[kc][i][h] = sum_{k in kc} adj[i][k] * X[k][h]
// Block b = kc*64 + hc*16 + ic: K-chunk 256, h-chunk 32, i-chunk 64 (wave=16 i).
__global__ __launch_bounds__(256) void k_adjmm(const float* __restrict__ X,
                                               const float* __restrict__ adj,
                                               float* __restrict__ part) {
  __shared__ short xt[32][264];            // 16.5 KB
  int t = threadIdx.x;
  int w = t >> 6, lane = t & 63;
  int c = lane & 15, g = lane >> 4;
  int b = blockIdx.x;
  int ic = b & 15, hc = (b >> 4) & 3, kc = b >> 6;
  int i0 = ic * 64 + w * 16, h0 = hc * 32;
  int k0 = kc * 256;

  {  // thread t stages row k = k0+t (32 floats from h0) into column t of xt
    const float* xr = X + (size_t)(k0 + t) * DD + h0;
    #pragma unroll
    for (int c8 = 0; c8 < 4; ++c8) {
      float4 v0 = *(const float4*)(xr + c8 * 8);
      float4 v1 = *(const float4*)(xr + c8 * 8 + 4);
      xt[c8 * 8 + 0][t] = f2bf(v0.x);
      xt[c8 * 8 + 1][t] = f2bf(v0.y);
      xt[c8 * 8 + 2][t] = f2bf(v0.z);
      xt[c8 * 8 + 3][t] = f2bf(v0.w);
      xt[c8 * 8 + 4][t] = f2bf(v1.x);
      xt[c8 * 8 + 5][t] = f2bf(v1.y);
      xt[c8 * 8 + 6][t] = f2bf(v1.z);
      xt[c8 * 8 + 7][t] = f2bf(v1.w);
    }
  }
  __syncthreads();

  f32x4 acc0 = {0, 0, 0, 0}, acc1 = {0, 0, 0, 0};
  const short* xa0 = &xt[c][8 * g];
  const short* xa1 = &xt[16 + c][8 * g];
  const float* ba  = adj + (size_t)(i0 + c) * NN + k0 + 8 * g;
  #pragma unroll
  for (int ks = 0; ks < 8; ++ks) {
    short8v a0 = *(const short8v*)(xa0 + ks * 32);
    short8v a1 = *(const short8v*)(xa1 + ks * 32);
    float4 b0 = *(const float4*)(ba + ks * 32);
    float4 b1 = *(const float4*)(ba + ks * 32 + 4);
    short8v bb;
    bb[0] = f2bf(b0.x); bb[1] = f2bf(b0.y); bb[2] = f2bf(b0.z); bb[3] = f2bf(b0.w);
    bb[4] = f2bf(b1.x); bb[5] = f2bf(b1.y); bb[6] = f2bf(b1.z); bb[7] = f2bf(b1.w);
    acc0 = __builtin_amdgcn_mfma_f32_16x16x32_bf16(a0, bb, acc0, 0, 0, 0);
    acc1 = __builtin_amdgcn_mfma_f32_16x16x32_bf16(a1, bb, acc1, 0, 0, 0);
  }
  float* p0 = part + ((size_t)kc * NN + (i0 + c)) * DD + h0 + 4 * g;
  float4 o0 = {acc0[0], acc0[1], acc0[2], acc0[3]};
  float4 o1 = {acc1[0], acc1[1], acc1[2], acc1[3]};
  *(float4*)(p0)      = o0;
  *(float4*)(p0 + 16) = o1;
}

// ---------------- K_dense1: rowsum + aggfin + dense layer1 ----------------
__global__ __launch_bounds__(256) void k_dense1(const float* __restrict__ X,
                                                const float* __restrict__ part,
                                                const float* __restrict__ adj,
                                                const float* __restrict__ W,
                                                const float* __restrict__ b,
                                                float* __restrict__ out,
                                                float* __restrict__ rsinv) {
  __shared__ float sagg[2][128];
  __shared__ float red[4];
  int t = threadIdx.x;
  int ig = t >> 7, h = t & 127;
  int i = blockIdx.x * 2 + ig;
  {
    const float4* ar = (const float4*)(adj + (size_t)i * NN);
    float4 v0 = ar[h * 2], v1 = ar[h * 2 + 1];
    float s = v0.x + v0.y + v0.z + v0.w + v1.x + v1.y + v1.z + v1.w;
    #pragma unroll
    for (int off = 32; off > 0; off >>= 1) s += __shfl_down(s, off, 64);
    if ((t & 63) == 0) red[t >> 6] = s;
  }
  __syncthreads();
  float rs = 1.0f / (red[ig * 2] + red[ig * 2 + 1] + 1e-6f);
  if (h == 0) rsinv[i] = rs;
  {
    float ss = 0.f;
    #pragma unroll
    for (int kc = 0; kc < 4; ++kc) ss += part[(size_t)kc * NN * DD + (size_t)i * DD + h];
    sagg[ig][h] = ss * rs;
  }
  __syncthreads();
  const float4* xr = (const float4*)(X + (size_t)i * DD);
  const float4* ar = (const float4*)(&sagg[ig][0]);
  const float4* w1 = (const float4*)(W + (size_t)h * 256);
  const float4* w2 = (const float4*)(W + (size_t)h * 256 + DD);
  float acc = b[h];
  #pragma unroll 8
  for (int k = 0; k < 32; ++k) {
    float4 x = xr[k], w = w1[k];
    acc += x.x * w.x + x.y * w.y + x.z * w.z + x.w * w.w;
  }
  #pragma unroll 8
  for (int k = 0; k < 32; ++k) {
    float4 y = ar[k], w = w2[k];
    acc += y.x * w.x + y.y * w.y + y.z * w.z + y.w * w.w;
  }
  out[(size_t)i * DD + h] = fmaxf(acc, 0.f);
}

// ---------------- K_dense2ab: aggfin + dense layer2 + Aib/Bmat, fused ------------
__global__ __launch_bounds__(256) void k_dense2ab(const float* __restrict__ X,
                                                  const float* __restrict__ part,
                                                  const float* __restrict__ rsinv,
                                                  const float* __restrict__ W,
                                                  const float* __restrict__ b,
                                                  const float* __restrict__ Wc1,
                                                  const float* __restrict__ bc1,
                                                  float* __restrict__ Aib,
                                                  float* __restrict__ Bmat) {
  __shared__ float sagg[2][128];
  __shared__ float sh2[2][128];
  int t = threadIdx.x;
  int ig = t >> 7, h = t & 127;
  int i = blockIdx.x * 2 + ig;
  {
    float ss = 0.f;
    #pragma unroll
    for (int kc = 0; kc < 4; ++kc) ss += part[(size_t)kc * NN * DD + (size_t)i * DD + h];
    sagg[ig][h] = ss * rsinv[i];
  }
  __syncthreads();
  {
    const float4* xr = (const float4*)(X + (size_t)i * DD);
    const float4* ar = (const float4*)(&sagg[ig][0]);
    const float4* w1 = (const float4*)(W + (size_t)h * 256);
    const float4* w2 = (const float4*)(W + (size_t)h * 256 + DD);
    float acc = b[h];
    #pragma unroll 8
    for (int k = 0; k < 32; ++k) {
      float4 x = xr[k], w = w1[k];
      acc += x.x * w.x + x.y * w.y + x.z * w.z + x.w * w.w;
    }
    #pragma unroll 8
    for (int k = 0; k < 32; ++k) {
      float4 y = ar[k], w = w2[k];
      acc += y.x * w.x + y.y * w.y + y.z * w.z + y.w * w.w;
    }
    sh2[ig][h] = fmaxf(acc, 0.f);
  }
  __syncthreads();
  const float4* xr = (const float4*)(&sh2[ig][0]);
  const float4* wa = (const float4*)(Wc1 + (size_t)h * 288);
  const float4* wb = (const float4*)(Wc1 + (size_t)h * 288 + 128);
  float aa = bc1[h], bb = 0.f;
  #pragma unroll 8
  for (int k = 0; k < 32; ++k) {
    float4 x = xr[k];
    float4 a = wa[k], b2 = wb[k];
    aa += x.x * a.x + x.y * a.y + x.z * a.z + x.w * a.w;
    bb += x.x * b2.x + x.y * b2.y + x.z * b2.z + x.w * b2.w;
  }
  Aib[(size_t)i * DD + h] = aa;
  Bmat[(size_t)i * DD + h] = bb;
}

// ---------------- K7: fused edge stage (v12, reverted from R14 — measured 77 µs) --
#define EDGE_BODY(T, S, PF) do {                                              \
    float4 a_ = eA##S, b_ = eB##S;                                            \
    if (PF) {                                                                 \
      const float* p_ = ebl + (size_t)((T) + 6) * ((size_t)NN * EDIM);        \
      eA##S = *(const float4*)p_;                                             \
      eB##S = *(const float4*)(p_ + 4);                                       \
    }                                                                         \
    short8v ef_;                                                              \
    ef_[0]=f2bf(a_.x); ef_[1]=f2bf(a_.y); ef_[2]=f2bf(a_.z); ef_[3]=f2bf(a_.w); \
    ef_[4]=f2bf(b_.x); ef_[5]=f2bf(b_.y); ef_[6]=f2bf(b_.z); ef_[7]=f2bf(b_.w); \
    char* pw_ = psm + (((T) & 1) << 12);                                      \
    const float* ap_ = aibs + (T) * 128 + 4 * g;                              \
    _Pragma("unroll")                                                         \
    for (int n = 0; n < 8; ++n) {                                             \
      float4 av_ = *(const float4*)(ap_ + 16 * n);                            \
      f32x4 ci_;                                                              \
      ci_[0] = av_.x + bjv[n].x; ci_[1] = av_.y + bjv[n].y;                   \
      ci_[2] = av_.z + bjv[n].z; ci_[3] = av_.w + bjv[n].w;                   \
      f32x4 acc_ = __builtin_amdgcn_mfma_f32_16x16x32_bf16(weF[n], ef_, ci_, 0, 0, 0); \
      short4v pk_;                                                            \
      pk_[0] = f2bf(fmaxf(acc_[0], 0.f)); pk_[1] = f2bf(fmaxf(acc_[1], 0.f)); \
      pk_[2] = f2bf(fmaxf(acc_[2], 0.f)); pk_[3] = f2bf(fmaxf(acc_[3], 0.f)); \
      *(short4v*)(pw_ + (((n >> 1) << 10) + ((n & 1) << 9) + wroff)) = pk_;   \
    }                                                                         \
  } while (0)

#define G2(G2T, OREG) do {                                                    \
    f32x4 a2_;                                                                \
    a2_[0] = bc2v.x; a2_[1] = bc2v.y; a2_[2] = bc2v.z; a2_[3] = bc2v.w;       \
    const char* pp_ = psm + (((G2T) & 1) << 12);                              \
    _Pragma("unroll")                                                         \
    for (int kk = 0; kk < 4; ++kk) {                                          \
      short8v pb_ = *(const short8v*)(pp_ + ((kk << 10) + rdP));              \
      a2_ = __builtin_amdgcn_mfma_f32_16x16x32_bf16(wcF[kk], pb_, a2_, 0, 0, 0); \
    }                                                                         \
    bool dg_ = (j == i0 + (G2T));                                             \
    OREG.x = dg_ ? 0.f : a2_[0];                                              \
    OREG.y = dg_ ? 0.f : a2_[1];                                              \
    OREG.z = dg_ ? 0.f : a2_[2];                                              \
    OREG.w = dg_ ? 0.f : a2_[3];                                              \
  } while (0)

#define FLUSH(BASE) do {                                                      \
    nt_store4(out + ((size_t)(i0 + (BASE) + 0) * NN + j) * NR + 4 * g, o0);   \
    nt_store4(out + ((size_t)(i0 + (BASE) + 1) * NN + j) * NR + 4 * g, o1);   \
    nt_store4(out + ((size_t)(i0 + (BASE) + 2) * NN + j) * NR + 4 * g, o2);   \
    nt_store4(out + ((size_t)(i0 + (BASE) + 3) * NN + j) * NR + 4 * g, o3);   \
  } while (0)

__global__ __launch_bounds__(256, 1) void k_edge(const float* __restrict__ edge,
                                                 const float* __restrict__ Wc1,
                                                 const float* __restrict__ Wc2,
                                                 const float* __restrict__ bc2,
                                                 const float* __restrict__ Aib,
                                                 const float* __restrict__ Bmat,
                                                 float* __restrict__ out) {
  __shared__ __align__(16) char psm_all[4][2][4096]; // 32 KB P tiles (dbuf per wave)
  __shared__ __align__(16) float aibs[16 * 128];     // 8 KB Aib panel -> 40 KB total
  int tid = threadIdx.x;
  int w = tid >> 6, lane = tid & 63;
  int c = lane & 15, g = lane >> 4;
  int ig = blockIdx.x >> 4, jg = blockIdx.x & 15;
  int i0 = ig * 16;
  int j0w = jg * 64 + w * 16;
  int j = j0w + c;

  {
    int ii = tid >> 4, h8 = (tid & 15) * 8;
    const float4* s = (const float4*)(Aib + (size_t)(i0 + ii) * DD + h8);
    *(float4*)(aibs + ii * 128 + h8)     = s[0];
    *(float4*)(aibs + ii * 128 + h8 + 4) = s[1];
  }

  short8v weF[8];
  #pragma unroll
  for (int n = 0; n < 8; ++n) {
    const float* p = Wc1 + (size_t)(16 * n + c) * 288 + 256 + 8 * g;
    float4 f0 = *(const float4*)p;
    float4 f1 = *(const float4*)(p + 4);
    short8v s;
    s[0]=f2bf(f0.x); s[1]=f2bf(f0.y); s[2]=f2bf(f0.z); s[3]=f2bf(f0.w);
    s[4]=f2bf(f1.x); s[5]=f2bf(f1.y); s[6]=f2bf(f1.z); s[7]=f2bf(f1.w);
    weF[n] = s;
  }
  short8v wcF[4];
  #pragma unroll
  for (int kk = 0; kk < 4; ++kk) {
    const float* p = Wc2 + (size_t)c * DD + 32 * kk + 8 * g;
    float4 f0 = *(const float4*)p;
    float4 f1 = *(const float4*)(p + 4);
    short8v s;
    s[0]=f2bf(f0.x); s[1]=f2bf(f0.y); s[2]=f2bf(f0.z); s[3]=f2bf(f0.w);
    s[4]=f2bf(f1.x); s[5]=f2bf(f1.y); s[6]=f2bf(f1.z); s[7]=f2bf(f1.w);
    wcF[kk] = s;
  }
  float4 bc2v = *(const float4*)(bc2 + 4 * g);
  float4 bjv[8];
  #pragma unroll
  for (int n = 0; n < 8; ++n)
    bjv[n] = *(const float4*)(Bmat + (size_t)j * DD + 16 * n + 4 * g);

  __syncthreads();   // aibs ready

  char* psm = &psm_all[w][0][0];
  const float* ebl = edge + ((size_t)i0 * NN + j) * EDIM + 8 * g;
  int wroff = (c << 4) + ((g & 1) << 3) + ((g >> 1) << 8);
  int rdP   = (g << 8) + (c << 4);

  float4 o0, o1, o2, o3;

  float4 eA0, eB0, eA1, eB1, eA2, eB2, eA3, eB3, eA4, eB4, eA5, eB5;
  {
    const size_t STP = (size_t)NN * EDIM;
    eA0 = *(const float4*)(ebl);            eB0 = *(const float4*)(ebl + 4);
    eA1 = *(const float4*)(ebl + STP);      eB1 = *(const float4*)(ebl + STP + 4);
    eA2 = *(const float4*)(ebl + 2 * STP);  eB2 = *(const float4*)(ebl + 2 * STP + 4);
    eA3 = *(const float4*)(ebl + 3 * STP);  eB3 = *(const float4*)(ebl + 3 * STP + 4);
    eA4 = *(const float4*)(ebl + 4 * STP);  eB4 = *(const float4*)(ebl + 4 * STP + 4);
    eA5 = *(const float4*)(ebl + 5 * STP);  eB5 = *(const float4*)(ebl + 5 * STP + 4);
  }

  EDGE_BODY(0, 0, 1);
  EDGE_BODY(1, 1, 1);  G2(0, o0);
  EDGE_BODY(2, 2, 1);  G2(1, o1);
  EDGE_BODY(3, 3, 1);  G2(2, o2);
  EDGE_BODY(4, 4, 1);  G2(3, o3);  FLUSH(0);
  EDGE_BODY(5, 5, 1);  G2(4, o0);
  EDGE_BODY(6, 0, 1);  G2(5, o1);
  EDGE_BODY(7, 1, 1);  G2(6, o2);
  EDGE_BODY(8, 2, 1);  G2(7, o3);  FLUSH(4);
  EDGE_BODY(9, 3, 1);  G2(8, o0);
  EDGE_BODY(10, 4, 0); G2(9, o1);
  EDGE_BODY(11, 5, 0); G2(10, o2);
  EDGE_BODY(12, 0, 0); G2(11, o3); FLUSH(8);
  EDGE_BODY(13, 1, 0); G2(12, o0);
  EDGE_BODY(14, 2, 0); G2(13, o1);
  EDGE_BODY(15, 3, 0); G2(14, o2);
  G2(15, o3); FLUSH(12);
}

extern "C" void kernel_launch(void* const* d_in, const int* in_sizes, int n_in,
                              void* d_out, int out_size, void* d_ws, size_t ws_size,
                              hipStream_t stream) {
  const float* node_feat = (const float*)d_in[0];
  const float* edge_feat = (const float*)d_in[1];
  const float* adj  = (const float*)d_in[2];
  const float* W_g1 = (const float*)d_in[3];
  const float* b_g1 = (const float*)d_in[4];
  const float* W_g2 = (const float*)d_in[5];
  const float* b_g2 = (const float*)d_in[6];
  const float* W_c1 = (const float*)d_in[7];
  const float* b_c1 = (const float*)d_in[8];
  const float* W_c2 = (const float*)d_in[9];
  const float* b_c2 = (const float*)d_in[10];
  float* out = (float*)d_out;

  float* ws    = (float*)d_ws;
  float* rsinv = ws;                        // 1024
  float* part  = ws + 1024;                 // 4*1024*128 = 524288
  float* h1    = part + 4 * NN * DD;        // 131072
  float* Aib   = h1 + NN * DD;              // 131072
  float* Bmat  = Aib + NN * DD;             // 131072

  // layer 1: fused-transpose MFMA adj@X -> dense (rowsum fused)
  k_adjmm<<<256, 256, 0, stream>>>(node_feat, adj, part);
  k_dense1<<<512, 256, 0, stream>>>(node_feat, part, adj, W_g1, b_g1, h1, rsinv);
  // layer 2
  k_adjmm<<<256, 256, 0, stream>>>(h1, adj, part);
  k_dense2ab<<<512, 256, 0, stream>>>(h1, part, rsinv, W_g2, b_g2, W_c1, b_c1, Aib, Bmat);
  // fused edge stage (R14 v12 revert)
  k_edge<<<1024, 256, 0, stream>>>(edge_feat, W_c1, W_c2, b_c2, Aib, Bmat, out);
}

// Round 18
// 114.986 us; speedup vs baseline: 2.0558x; 1.0032x over previous
//
#include <hip/hip_runtime.h>
#include <hip/hip_bf16.h>
#include <stdint.h>

constexpr int NN = 1024;   // nodes
constexpr int DD = 128;    // NODE_DIM == HID
constexpr int EDIM = 32;   // EDGE_DIM
constexpr int NR = 16;     // NREL

using short4v = __attribute__((ext_vector_type(4))) short;
using short8v = __attribute__((ext_vector_type(8))) short;
using f32x4   = __attribute__((ext_vector_type(4))) float;

__device__ __forceinline__ short f2bf(float x) {
  __hip_bfloat16 h = __float2bfloat16(x);   // RNE
  return __builtin_bit_cast(short, h);
}

__device__ __forceinline__ void nt_store4(float* p, const float4& v) {
  f32x4 t;
  t[0] = v.x; t[1] = v.y; t[2] = v.z; t[3] = v.w;
  __builtin_nontemporal_store(t, (f32x4*)p);
}

// ---------------- K_adjmm (fused f32->bf16 transpose stage + MFMA) ----------
__global__ __launch_bounds__(256) void k_adjmm(const float* __restrict__ X,
                                               const float* __restrict__ adj,
                                               float* __restrict__ part) {
  __shared__ short xt[32][264];            // 16.5 KB
  int t = threadIdx.x;
  int w = t >> 6, lane = t & 63;
  int c = lane & 15, g = lane >> 4;
  int b = blockIdx.x;
  int ic = b & 15, hc = (b >> 4) & 3, kc = b >> 6;
  int i0 = ic * 64 + w * 16, h0 = hc * 32;
  int k0 = kc * 256;

  {  // thread t stages row k = k0+t (32 floats from h0) into column t of xt
    const float* xr = X + (size_t)(k0 + t) * DD + h0;
    #pragma unroll
    for (int c8 = 0; c8 < 4; ++c8) {
      float4 v0 = *(const float4*)(xr + c8 * 8);
      float4 v1 = *(const float4*)(xr + c8 * 8 + 4);
      xt[c8 * 8 + 0][t] = f2bf(v0.x);
      xt[c8 * 8 + 1][t] = f2bf(v0.y);
      xt[c8 * 8 + 2][t] = f2bf(v0.z);
      xt[c8 * 8 + 3][t] = f2bf(v0.w);
      xt[c8 * 8 + 4][t] = f2bf(v1.x);
      xt[c8 * 8 + 5][t] = f2bf(v1.y);
      xt[c8 * 8 + 6][t] = f2bf(v1.z);
      xt[c8 * 8 + 7][t] = f2bf(v1.w);
    }
  }
  __syncthreads();

  f32x4 acc0 = {0, 0, 0, 0}, acc1 = {0, 0, 0, 0};
  const short* xa0 = &xt[c][8 * g];
  const short* xa1 = &xt[16 + c][8 * g];
  const float* ba  = adj + (size_t)(i0 + c) * NN + k0 + 8 * g;
  #pragma unroll
  for (int ks = 0; ks < 8; ++ks) {
    short8v a0 = *(const short8v*)(xa0 + ks * 32);
    short8v a1 = *(const short8v*)(xa1 + ks * 32);
    float4 b0 = *(const float4*)(ba + ks * 32);
    float4 b1 = *(const float4*)(ba + ks * 32 + 4);
    short8v bb;
    bb[0] = f2bf(b0.x); bb[1] = f2bf(b0.y); bb[2] = f2bf(b0.z); bb[3] = f2bf(b0.w);
    bb[4] = f2bf(b1.x); bb[5] = f2bf(b1.y); bb[6] = f2bf(b1.z); bb[7] = f2bf(b1.w);
    acc0 = __builtin_amdgcn_mfma_f32_16x16x32_bf16(a0, bb, acc0, 0, 0, 0);
    acc1 = __builtin_amdgcn_mfma_f32_16x16x32_bf16(a1, bb, acc1, 0, 0, 0);
  }
  float* p0 = part + ((size_t)kc * NN + (i0 + c)) * DD + h0 + 4 * g;
  float4 o0 = {acc0[0], acc0[1], acc0[2], acc0[3]};
  float4 o1 = {acc1[0], acc1[1], acc1[2], acc1[3]};
  *(float4*)(p0)      = o0;
  *(float4*)(p0 + 16) = o1;
}

// ---------------- K_dense1: rowsum + aggfin + dense layer1 ----------------
__global__ __launch_bounds__(256) void k_dense1(const float* __restrict__ X,
                                                const float* __restrict__ part,
                                                const float* __restrict__ adj,
                                                const float* __restrict__ W,
                                                const float* __restrict__ b,
                                                float* __restrict__ out,
                                                float* __restrict__ rsinv) {
  __shared__ float sagg[2][128];
  __shared__ float red[4];
  int t = threadIdx.x;
  int ig = t >> 7, h = t & 127;
  int i = blockIdx.x * 2 + ig;
  {
    const float4* ar = (const float4*)(adj + (size_t)i * NN);
    float4 v0 = ar[h * 2], v1 = ar[h * 2 + 1];
    float s = v0.x + v0.y + v0.z + v0.w + v1.x + v1.y + v1.z + v1.w;
    #pragma unroll
    for (int off = 32; off > 0; off >>= 1) s += __shfl_down(s, off, 64);
    if ((t & 63) == 0) red[t >> 6] = s;
  }
  __syncthreads();
  float rs = 1.0f / (red[ig * 2] + red[ig * 2 + 1] + 1e-6f);
  if (h == 0) rsinv[i] = rs;
  {
    float ss = 0.f;
    #pragma unroll
    for (int kc = 0; kc < 4; ++kc) ss += part[(size_t)kc * NN * DD + (size_t)i * DD + h];
    sagg[ig][h] = ss * rs;
  }
  __syncthreads();
  const float4* xr = (const float4*)(X + (size_t)i * DD);
  const float4* ar = (const float4*)(&sagg[ig][0]);
  const float4* w1 = (const float4*)(W + (size_t)h * 256);
  const float4* w2 = (const float4*)(W + (size_t)h * 256 + DD);
  float acc = b[h];
  #pragma unroll 8
  for (int k = 0; k < 32; ++k) {
    float4 x = xr[k], w = w1[k];
    acc += x.x * w.x + x.y * w.y + x.z * w.z + x.w * w.w;
  }
  #pragma unroll 8
  for (int k = 0; k < 32; ++k) {
    float4 y = ar[k], w = w2[k];
    acc += y.x * w.x + y.y * w.y + y.z * w.z + y.w * w.w;
  }
  out[(size_t)i * DD + h] = fmaxf(acc, 0.f);
}

// ---------------- K_dense2ab: aggfin + dense layer2 + Aib/Bmat, fused ------------
__global__ __launch_bounds__(256) void k_dense2ab(const float* __restrict__ X,
                                                  const float* __restrict__ part,
                                                  const float* __restrict__ rsinv,
                                                  const float* __restrict__ W,
                                                  const float* __restrict__ b,
                                                  const float* __restrict__ Wc1,
                                                  const float* __restrict__ bc1,
                                                  float* __restrict__ Aib,
                                                  float* __restrict__ Bmat) {
  __shared__ float sagg[2][128];
  __shared__ float sh2[2][128];
  int t = threadIdx.x;
  int ig = t >> 7, h = t & 127;
  int i = blockIdx.x * 2 + ig;
  {
    float ss = 0.f;
    #pragma unroll
    for (int kc = 0; kc < 4; ++kc) ss += part[(size_t)kc * NN * DD + (size_t)i * DD + h];
    sagg[ig][h] = ss * rsinv[i];
  }
  __syncthreads();
  {
    const float4* xr = (const float4*)(X + (size_t)i * DD);
    const float4* ar = (const float4*)(&sagg[ig][0]);
    const float4* w1 = (const float4*)(W + (size_t)h * 256);
    const float4* w2 = (const float4*)(W + (size_t)h * 256 + DD);
    float acc = b[h];
    #pragma unroll 8
    for (int k = 0; k < 32; ++k) {
      float4 x = xr[k], w = w1[k];
      acc += x.x * w.x + x.y * w.y + x.z * w.z + x.w * w.w;
    }
    #pragma unroll 8
    for (int k = 0; k < 32; ++k) {
      float4 y = ar[k], w = w2[k];
      acc += y.x * w.x + y.y * w.y + y.z * w.z + y.w * w.w;
    }
    sh2[ig][h] = fmaxf(acc, 0.f);
  }
  __syncthreads();
  const float4* xr = (const float4*)(&sh2[ig][0]);
  const float4* wa = (const float4*)(Wc1 + (size_t)h * 288);
  const float4* wb = (const float4*)(Wc1 + (size_t)h * 288 + 128);
  float aa = bc1[h], bb = 0.f;
  #pragma unroll 8
  for (int k = 0; k < 32; ++k) {
    float4 x = xr[k];
    float4 a = wa[k], b2 = wb[k];
    aa += x.x * a.x + x.y * a.y + x.z * a.z + x.w * a.w;
    bb += x.x * b2.x + x.y * b2.y + x.z * b2.z + x.w * b2.w;
  }
  Aib[(size_t)i * DD + h] = aa;
  Bmat[(size_t)i * DD + h] = bb;
}

// ---------------- K7: fused edge stage (v14 = v12 + XCD-chunked block swizzle) ----
// T1 (m157): logical block L = (bid%8)*128 + bid/8 (bijective, 1024%8==0).
// The 16 blocks sharing an ig (same 2MB of edge rows + same Aib panel) now land
// on ONE XCD's L2 instead of being duplicated across all 8 private L2s.
#define EDGE_BODY(T, S, PF) do {                                              \
    float4 a_ = eA##S, b_ = eB##S;                                            \
    if (PF) {                                                                 \
      const float* p_ = ebl + (size_t)((T) + 6) * ((size_t)NN * EDIM);        \
      eA##S = *(const float4*)p_;                                             \
      eB##S = *(const float4*)(p_ + 4);                                       \
    }                                                                         \
    short8v ef_;                                                              \
    ef_[0]=f2bf(a_.x); ef_[1]=f2bf(a_.y); ef_[2]=f2bf(a_.z); ef_[3]=f2bf(a_.w); \
    ef_[4]=f2bf(b_.x); ef_[5]=f2bf(b_.y); ef_[6]=f2bf(b_.z); ef_[7]=f2bf(b_.w); \
    char* pw_ = psm + (((T) & 1) << 12);                                      \
    const float* ap_ = aibs + (T) * 128 + 4 * g;                              \
    _Pragma("unroll")                                                         \
    for (int n = 0; n < 8; ++n) {                                             \
      float4 av_ = *(const float4*)(ap_ + 16 * n);                            \
      f32x4 ci_;                                                              \
      ci_[0] = av_.x + bjv[n].x; ci_[1] = av_.y + bjv[n].y;                   \
      ci_[2] = av_.z + bjv[n].z; ci_[3] = av_.w + bjv[n].w;                   \
      f32x4 acc_ = __builtin_amdgcn_mfma_f32_16x16x32_bf16(weF[n], ef_, ci_, 0, 0, 0); \
      short4v pk_;                                                            \
      pk_[0] = f2bf(fmaxf(acc_[0], 0.f)); pk_[1] = f2bf(fmaxf(acc_[1], 0.f)); \
      pk_[2] = f2bf(fmaxf(acc_[2], 0.f)); pk_[3] = f2bf(fmaxf(acc_[3], 0.f)); \
      *(short4v*)(pw_ + (((n >> 1) << 10) + ((n & 1) << 9) + wroff)) = pk_;   \
    }                                                                         \
  } while (0)

#define G2(G2T, OREG) do {                                                    \
    f32x4 a2_;                                                                \
    a2_[0] = bc2v.x; a2_[1] = bc2v.y; a2_[2] = bc2v.z; a2_[3] = bc2v.w;       \
    const char* pp_ = psm + (((G2T) & 1) << 12);                              \
    _Pragma("unroll")                                                         \
    for (int kk = 0; kk < 4; ++kk) {                                          \
      short8v pb_ = *(const short8v*)(pp_ + ((kk << 10) + rdP));              \
      a2_ = __builtin_amdgcn_mfma_f32_16x16x32_bf16(wcF[kk], pb_, a2_, 0, 0, 0); \
    }                                                                         \
    bool dg_ = (j == i0 + (G2T));                                             \
    OREG.x = dg_ ? 0.f : a2_[0];                                              \
    OREG.y = dg_ ? 0.f : a2_[1];                                              \
    OREG.z = dg_ ? 0.f : a2_[2];                                              \
    OREG.w = dg_ ? 0.f : a2_[3];                                              \
  } while (0)

#define FLUSH(BASE) do {                                                      \
    nt_store4(out + ((size_t)(i0 + (BASE) + 0) * NN + j) * NR + 4 * g, o0);   \
    nt_store4(out + ((size_t)(i0 + (BASE) + 1) * NN + j) * NR + 4 * g, o1);   \
    nt_store4(out + ((size_t)(i0 + (BASE) + 2) * NN + j) * NR + 4 * g, o2);   \
    nt_store4(out + ((size_t)(i0 + (BASE) + 3) * NN + j) * NR + 4 * g, o3);   \
  } while (0)

__global__ __launch_bounds__(256, 1) void k_edge(const float* __restrict__ edge,
                                                 const float* __restrict__ Wc1,
                                                 const float* __restrict__ Wc2,
                                                 const float* __restrict__ bc2,
                                                 const float* __restrict__ Aib,
                                                 const float* __restrict__ Bmat,
                                                 float* __restrict__ out) {
  __shared__ __align__(16) char psm_all[4][2][4096]; // 32 KB P tiles (dbuf per wave)
  __shared__ __align__(16) float aibs[16 * 128];     // 8 KB Aib panel -> 40 KB total
  int tid = threadIdx.x;
  int w = tid >> 6, lane = tid & 63;
  int c = lane & 15, g = lane >> 4;
  int bid = blockIdx.x;
  int lb  = (bid & 7) * 128 + (bid >> 3);   // XCD-chunked logical block (T1)
  int ig = lb >> 4, jg = lb & 15;
  int i0 = ig * 16;
  int j0w = jg * 64 + w * 16;
  int j = j0w + c;

  {
    int ii = tid >> 4, h8 = (tid & 15) * 8;
    const float4* s = (const float4*)(Aib + (size_t)(i0 + ii) * DD + h8);
    *(float4*)(aibs + ii * 128 + h8)     = s[0];
    *(float4*)(aibs + ii * 128 + h8 + 4) = s[1];
  }

  short8v weF[8];
  #pragma unroll
  for (int n = 0; n < 8; ++n) {
    const float* p = Wc1 + (size_t)(16 * n + c) * 288 + 256 + 8 * g;
    float4 f0 = *(const float4*)p;
    float4 f1 = *(const float4*)(p + 4);
    short8v s;
    s[0]=f2bf(f0.x); s[1]=f2bf(f0.y); s[2]=f2bf(f0.z); s[3]=f2bf(f0.w);
    s[4]=f2bf(f1.x); s[5]=f2bf(f1.y); s[6]=f2bf(f1.z); s[7]=f2bf(f1.w);
    weF[n] = s;
  }
  short8v wcF[4];
  #pragma unroll
  for (int kk = 0; kk < 4; ++kk) {
    const float* p = Wc2 + (size_t)c * DD + 32 * kk + 8 * g;
    float4 f0 = *(const float4*)p;
    float4 f1 = *(const float4*)(p + 4);
    short8v s;
    s[0]=f2bf(f0.x); s[1]=f2bf(f0.y); s[2]=f2bf(f0.z); s[3]=f2bf(f0.w);
    s[4]=f2bf(f1.x); s[5]=f2bf(f1.y); s[6]=f2bf(f1.z); s[7]=f2bf(f1.w);
    wcF[kk] = s;
  }
  float4 bc2v = *(const float4*)(bc2 + 4 * g);
  float4 bjv[8];
  #pragma unroll
  for (int n = 0; n < 8; ++n)
    bjv[n] = *(const float4*)(Bmat + (size_t)j * DD + 16 * n + 4 * g);

  __syncthreads();   // aibs ready

  char* psm = &psm_all[w][0][0];
  const float* ebl = edge + ((size_t)i0 * NN + j) * EDIM + 8 * g;
  int wroff = (c << 4) + ((g & 1) << 3) + ((g >> 1) << 8);
  int rdP   = (g << 8) + (c << 4);

  float4 o0, o1, o2, o3;

  float4 eA0, eB0, eA1, eB1, eA2, eB2, eA3, eB3, eA4, eB4, eA5, eB5;
  {
    const size_t STP = (size_t)NN * EDIM;
    eA0 = *(const float4*)(ebl);            eB0 = *(const float4*)(ebl + 4);
    eA1 = *(const float4*)(ebl + STP);      eB1 = *(const float4*)(ebl + STP + 4);
    eA2 = *(const float4*)(ebl + 2 * STP);  eB2 = *(const float4*)(ebl + 2 * STP + 4);
    eA3 = *(const float4*)(ebl + 3 * STP);  eB3 = *(const float4*)(ebl + 3 * STP + 4);
    eA4 = *(const float4*)(ebl + 4 * STP);  eB4 = *(const float4*)(ebl + 4 * STP + 4);
    eA5 = *(const float4*)(ebl + 5 * STP);  eB5 = *(const float4*)(ebl + 5 * STP + 4);
  }

  EDGE_BODY(0, 0, 1);
  EDGE_BODY(1, 1, 1);  G2(0, o0);
  EDGE_BODY(2, 2, 1);  G2(1, o1);
  EDGE_BODY(3, 3, 1);  G2(2, o2);
  EDGE_BODY(4, 4, 1);  G2(3, o3);  FLUSH(0);
  EDGE_BODY(5, 5, 1);  G2(4, o0);
  EDGE_BODY(6, 0, 1);  G2(5, o1);
  EDGE_BODY(7, 1, 1);  G2(6, o2);
  EDGE_BODY(8, 2, 1);  G2(7, o3);  FLUSH(4);
  EDGE_BODY(9, 3, 1);  G2(8, o0);
  EDGE_BODY(10, 4, 0); G2(9, o1);
  EDGE_BODY(11, 5, 0); G2(10, o2);
  EDGE_BODY(12, 0, 0); G2(11, o3); FLUSH(8);
  EDGE_BODY(13, 1, 0); G2(12, o0);
  EDGE_BODY(14, 2, 0); G2(13, o1);
  EDGE_BODY(15, 3, 0); G2(14, o2);
  G2(15, o3); FLUSH(12);
}

extern "C" void kernel_launch(void* const* d_in, const int* in_sizes, int n_in,
                              void* d_out, int out_size, void* d_ws, size_t ws_size,
                              hipStream_t stream) {
  const float* node_feat = (const float*)d_in[0];
  const float* edge_feat = (const float*)d_in[1];
  const float* adj  = (const float*)d_in[2];
  const float* W_g1 = (const float*)d_in[3];
  const float* b_g1 = (const float*)d_in[4];
  const float* W_g2 = (const float*)d_in[5];
  const float* b_g2 = (const float*)d_in[6];
  const float* W_c1 = (const float*)d_in[7];
  const float* b_c1 = (const float*)d_in[8];
  const float* W_c2 = (const float*)d_in[9];
  const float* b_c2 = (const float*)d_in[10];
  float* out = (float*)d_out;

  float* ws    = (float*)d_ws;
  float* rsinv = ws;                        // 1024
  float* part  = ws + 1024;                 // 4*1024*128 = 524288
  float* h1    = part + 4 * NN * DD;        // 131072
  float* Aib   = h1 + NN * DD;              // 131072
  float* Bmat  = Aib + NN * DD;             // 131072

  // layer 1: fused-transpose MFMA adj@X -> dense (rowsum fused)
  k_adjmm<<<256, 256, 0, stream>>>(node_feat, adj, part);
  k_dense1<<<512, 256, 0, stream>>>(node_feat, part, adj, W_g1, b_g1, h1, rsinv);
  // layer 2
  k_adjmm<<<256, 256, 0, stream>>>(h1, adj, part);
  k_dense2ab<<<512, 256, 0, stream>>>(h1, part, rsinv, W_g2, b_g2, W_c1, b_c1, Aib, Bmat);
  // fused edge stage (v14: + XCD-chunked swizzle)
  k_edge<<<1024, 256, 0, stream>>>(edge_feat, W_c1, W_c2, b_c2, Aib, Bmat, out);
}